// Round 3
// baseline (423.739 us; speedup 1.0000x reference)
//
#include <hip/hip_runtime.h>
#include <cfloat>

// Problem constants (match setup_inputs)
#define BB 4
#define NN 2000
#define MM 2000
#define KK 16
#define D_IN 34      // 2K+2
#define E1 128
#define E2 256
#define PEN -10.0f
#define EPSV 1e-5f
#define ROWS (BB*NN) // 8000

// ws float-offsets
#define OFF_H2  ((size_t)0)                         // ROWS*E2 floats
#define OFF_SD  (OFF_H2 + (size_t)ROWS*E2)          // ROWS*KK floats
#define OFF_SI  (OFF_SD + (size_t)ROWS*KK)          // ROWS*KK ints
#define OFF_ST  (OFF_SI + (size_t)ROWS*KK)          // 2*BB*E2 floats

// ---------------- kernel 1: topk(16 smallest, idx-tiebreak) + layers 1,2 ---
__global__ __launch_bounds__(256) void k1_topk_mlp(
    const float* __restrict__ theta, const float* __restrict__ dist,
    const float* __restrict__ ins,  // [2,B,N]
    const float* __restrict__ W1, const float* __restrict__ b1,
    const float* __restrict__ W2, const float* __restrict__ b2,
    float* __restrict__ ws)
{
    const int row = blockIdx.x;            // b*N+n
    const int b = row / NN, n = row % NN;
    const int t = threadIdx.x;
    const int lane = t & 63, wid = t >> 6;

    __shared__ float vals[MM];
    __shared__ unsigned int hist[2048];
    __shared__ unsigned long long cand[64];
    __shared__ int s_cnt, s_cut;
    __shared__ unsigned wsum[4];
    __shared__ float redv[4]; __shared__ int redi[4];
    __shared__ float sdv[KK]; __shared__ int sid[KK];
    __shared__ float xbuf[D_IN];
    __shared__ float h1[E1];

    // stage dist row in LDS (float4) + zero histogram
    {
        const float4* d4 = (const float4*)(dist + (size_t)row * MM);
        float4* v4 = (float4*)vals;
        for (int i = t; i < MM/4; i += 256) v4[i] = d4[i];
    }
    for (int i = t; i < 2048; i += 256) hist[i] = 0;
    if (t == 0) { s_cnt = 0; s_cut = 2047; }
    __syncthreads();

    // histogram over top-11 bits (monotone for non-negative floats)
    for (int i = t; i < MM; i += 256) {
        unsigned bin = __float_as_uint(vals[i]) >> 21;
        atomicAdd(&hist[bin], 1u);
    }
    __syncthreads();

    // block scan over 2048 bins (8 bins/thread) to find cutoff bin
    unsigned s = 0;
    #pragma unroll
    for (int j = 0; j < 8; ++j) s += hist[t*8 + j];
    unsigned v = s;
    #pragma unroll
    for (int d = 1; d < 64; d <<= 1) {
        unsigned o = __shfl_up(v, d);
        if (lane >= d) v += o;
    }
    if (lane == 63) wsum[wid] = v;
    __syncthreads();
    unsigned base = 0;
    for (int w = 0; w < wid; ++w) base += wsum[w];
    unsigned excl = base + v - s;             // exclusive prefix of this 8-bin group
    if (excl < KK && excl + s >= KK) {        // exactly one thread
        unsigned c = excl;
        #pragma unroll
        for (int j = 0; j < 8; ++j) {
            c += hist[t*8 + j];
            if (c >= KK) { s_cut = t*8 + j; break; }
        }
    }
    __syncthreads();
    const unsigned cut = (unsigned)s_cut;

    // collect all elements in bins <= cutoff (superset of the 16 smallest)
    for (int i = t; i < MM; i += 256) {
        unsigned bits = __float_as_uint(vals[i]);
        if ((bits >> 21) <= cut) {
            int p = atomicAdd(&s_cnt, 1);
            if (p < 64) cand[p] = ((unsigned long long)bits << 32) | (unsigned)i;
        }
    }
    __syncthreads();

    if (s_cnt <= 64) {
        // 64-lane bitonic sort of (valbits, idx) keys — exact top_k tiebreak
        if (t < 64) {
            unsigned long long key = (t < s_cnt) ? cand[t] : 0xFFFFFFFFFFFFFFFFull;
            #pragma unroll
            for (int k = 2; k <= 64; k <<= 1) {
                #pragma unroll
                for (int j = k >> 1; j > 0; j >>= 1) {
                    unsigned long long o = __shfl_xor(key, j);
                    bool keepMin = ((t & j) == 0) == ((t & k) == 0);
                    if (keepMin ? (o < key) : (o > key)) key = o;
                }
            }
            if (t < KK) {
                sdv[t] = __uint_as_float((unsigned)(key >> 32));
                sid[t] = (int)(key & 0xFFFFFFFFu);
            }
        }
    } else {
        // fallback (massive ties): exact 16-pass block argmin
        for (int it = 0; it < KK; ++it) {
            float mv = FLT_MAX; int mi = -1;
            for (int i = t; i < MM; i += 256) {
                float vv = vals[i];
                if (vv < mv || (vv == mv && i < mi)) { mv = vv; mi = i; }
            }
            #pragma unroll
            for (int off = 32; off; off >>= 1) {
                float ov = __shfl_down(mv, off);
                int   oi = __shfl_down(mi, off);
                if (ov < mv || (ov == mv && oi < mi)) { mv = ov; mi = oi; }
            }
            if (lane == 0) { redv[wid] = mv; redi[wid] = mi; }
            __syncthreads();
            if (t == 0) {
                mv = redv[0]; mi = redi[0];
                #pragma unroll
                for (int w = 1; w < 4; ++w) {
                    float ov = redv[w]; int oi = redi[w];
                    if (ov < mv || (ov == mv && oi < mi)) { mv = ov; mi = oi; }
                }
                sdv[it] = mv; sid[it] = mi;
                vals[mi] = FLT_MAX;
            }
            __syncthreads();
        }
    }
    __syncthreads();

    // normalize sorted_dist by its max (= last), gather theta, build x
    const float dmax = sdv[KK-1];
    if (t < KK) {
        float nd = sdv[t] / dmax;
        int   id = sid[t];
        xbuf[t]        = nd;
        xbuf[KK + t]   = theta[(size_t)row * MM + id];
        ws[OFF_SD + (size_t)row*KK + t] = nd;
        ((int*)(ws + OFF_SI))[(size_t)row*KK + t] = id;
    }
    if (t == 0) {
        xbuf[2*KK]     = ins[(size_t)b*NN + n];
        xbuf[2*KK + 1] = ins[(size_t)BB*NN + (size_t)b*NN + n];
    }
    __syncthreads();

    // layer 1: 34 -> 128, relu.  W1 row-major [128][34]; float2 marching.
    if (t < E1) {
        const float2* wp = (const float2*)(W1 + (size_t)t * D_IN); // 136B offset, 8B aligned
        float acc = b1[t];
        #pragma unroll
        for (int j = 0; j < D_IN/2; ++j) {
            float2 wv = wp[j];
            acc += wv.x * xbuf[2*j] + wv.y * xbuf[2*j + 1];
        }
        h1[t] = fmaxf(acc, 0.0f);
    }
    __syncthreads();

    // layer 2: 128 -> 256, relu.  W2 row-major [256][128]; float4 marching.
    {
        const float4* wp  = (const float4*)(W2 + (size_t)t * E1);  // 512B offset
        const float4* h14 = (const float4*)h1;
        float acc = b2[t];
        #pragma unroll 8
        for (int j = 0; j < E1/4; ++j) {
            float4 a = h14[j]; float4 w = wp[j];
            acc += a.x*w.x + a.y*w.y + a.z*w.z + a.w*w.w;
        }
        ws[OFF_H2 + (size_t)row*E2 + t] = fmaxf(acc, 0.0f);
    }
}

// ---------------- kernel 2: InstanceNorm statistics over N ----------------
#define CHUNK 50
#define NCHUNK (NN/CHUNK)   // 40
__global__ __launch_bounds__(256) void k2_stats(float* __restrict__ ws)
{
    const int b = blockIdx.x / NCHUNK;
    const int ch = blockIdx.x % NCHUNK;
    const int c = threadIdx.x;
    const float* p = ws + OFF_H2 + ((size_t)b*NN + (size_t)ch*CHUNK) * E2 + c;
    float s1 = 0.f, s2 = 0.f;
    #pragma unroll 5
    for (int r = 0; r < CHUNK; ++r) { float v = p[(size_t)r*E2]; s1 += v; s2 += v*v; }
    atomicAdd(&ws[OFF_ST + (size_t)b*E2 + c], s1);
    atomicAdd(&ws[OFF_ST + (size_t)BB*E2 + (size_t)b*E2 + c], s2);
}

// ---------------- kernel 3: norm + layers 3,4 + fill + scatter ------------
__global__ __launch_bounds__(256) void k3_norm_out(
    const float* __restrict__ W3, const float* __restrict__ b3,
    const float* __restrict__ W4, const float* __restrict__ b4,
    const float* __restrict__ gamma, const float* __restrict__ beta,
    const float* __restrict__ ws, float* __restrict__ out)
{
    const int row = blockIdx.x;
    const int b = row / NN;
    const int t = threadIdx.x;

    __shared__ float hn[E2];
    __shared__ float part3[2][E1];
    __shared__ float h3[E1];
    __shared__ float part4[KK][KK + 1];
    __shared__ float o16[KK];

    // normalize h2 (biased variance, eps inside sqrt)
    {
        float s1 = ws[OFF_ST + (size_t)b*E2 + t];
        float s2 = ws[OFF_ST + (size_t)BB*E2 + (size_t)b*E2 + t];
        float mu  = s1 / (float)NN;
        float var = s2 / (float)NN - mu*mu;
        float inv = 1.0f / sqrtf(var + EPSV);
        float v = ws[OFF_H2 + (size_t)row*E2 + t];
        hn[t] = (v - mu) * inv * gamma[t] + beta[t];
    }
    __syncthreads();

    // layer 3: 256 -> 128, relu. 256 threads = 128 channels x 2 K-halves.
    {
        const int c = t & (E1-1), half = t >> 7;
        const float4* wp  = (const float4*)(W3 + (size_t)c * E2 + (size_t)half * E1);
        const float4* hn4 = (const float4*)hn + half * (E1/4);
        float acc = 0.f;
        #pragma unroll 8
        for (int j = 0; j < E1/4; ++j) {
            float4 a = hn4[j]; float4 w = wp[j];
            acc += a.x*w.x + a.y*w.y + a.z*w.z + a.w*w.w;
        }
        part3[half][c] = acc;
    }
    __syncthreads();
    if (t < E1) h3[t] = fmaxf(part3[0][t] + part3[1][t] + b3[t], 0.0f);
    __syncthreads();

    // layer 4: 128 -> 16. 256 threads = 16 outputs x 16 K-chunks(8).
    {
        const int o = t & (KK-1), ch = t >> 4;
        const float4* wp  = (const float4*)(W4 + (size_t)o * E1 + (size_t)ch * 8);
        const float4* h34 = (const float4*)h3 + ch * 2;
        float4 a0 = h34[0], w0 = wp[0], a1 = h34[1], w1 = wp[1];
        part4[ch][o] = a0.x*w0.x + a0.y*w0.y + a0.z*w0.z + a0.w*w0.w
                     + a1.x*w1.x + a1.y*w1.y + a1.z*w1.z + a1.w*w1.w;
    }
    __syncthreads();
    if (t < KK) {
        float acc = b4[t];
        #pragma unroll
        for (int j = 0; j < KK; ++j) acc += part4[j][t];
        o16[t] = acc - ws[OFF_SD + (size_t)row*KK + t];
    }
    __syncthreads();

    // fill row with PENALTY (float4), then scatter the 16 outputs
    float* orow = out + (size_t)row * MM;
    float4* o4 = (float4*)orow;
    const float4 pv = make_float4(PEN, PEN, PEN, PEN);
    for (int i = t; i < MM/4; i += 256) o4[i] = pv;
    __syncthreads();
    if (t < KK) {
        int id = ((const int*)(ws + OFF_SI))[(size_t)row*KK + t];
        orow[id] = o16[t];
    }
}

extern "C" void kernel_launch(void* const* d_in, const int* in_sizes, int n_in,
                              void* d_out, int out_size, void* d_ws, size_t ws_size,
                              hipStream_t stream) {
    const float* theta = (const float*)d_in[0];
    const float* dist  = (const float*)d_in[1];
    const float* ins   = (const float*)d_in[2];
    const float* W1 = (const float*)d_in[3];
    const float* b1 = (const float*)d_in[4];
    const float* W2 = (const float*)d_in[5];
    const float* b2 = (const float*)d_in[6];
    const float* W3 = (const float*)d_in[7];
    const float* b3 = (const float*)d_in[8];
    const float* W4 = (const float*)d_in[9];
    const float* b4 = (const float*)d_in[10];
    const float* gamma = (const float*)d_in[11];
    const float* beta  = (const float*)d_in[12];
    float* ws  = (float*)d_ws;
    float* out = (float*)d_out;

    // zero the stats accumulators (ws is poisoned 0xAA before every launch)
    hipMemsetAsync(ws + OFF_ST, 0, (size_t)2*BB*E2*sizeof(float), stream);

    k1_topk_mlp<<<ROWS, 256, 0, stream>>>(theta, dist, ins, W1, b1, W2, b2, ws);
    k2_stats<<<BB*NCHUNK, 256, 0, stream>>>(ws);
    k3_norm_out<<<ROWS, 256, 0, stream>>>(W3, b3, W4, b4, gamma, beta, ws, out);
}

// Round 4
// 390.655 us; speedup vs baseline: 1.0847x; 1.0847x over previous
//
#include <hip/hip_runtime.h>
#include <cfloat>

// Problem constants (match setup_inputs)
#define BB 4
#define NN 2000
#define MM 2000
#define KK 16
#define D_IN 34      // 2K+2
#define E1 128
#define E2 256
#define PEN -10.0f
#define EPSV 1e-5f
#define ROWS (BB*NN) // 8000
#define RT 8         // rows per block in k3

// ws float-offsets
#define OFF_H2  ((size_t)0)                         // ROWS*E2 floats
#define OFF_SD  (OFF_H2 + (size_t)ROWS*E2)          // ROWS*KK floats
#define OFF_SI  (OFF_SD + (size_t)ROWS*KK)          // ROWS*KK ints
#define OFF_ST  (OFF_SI + (size_t)ROWS*KK)          // 2*BB*E2 floats (sum, sumsq)

typedef unsigned long long ull;

__device__ __forceinline__ ull shflx64(ull v, int m) {
    int lo = __shfl_xor((int)(unsigned)(v & 0xffffffffull), m, 64);
    int hi = __shfl_xor((int)(unsigned)(v >> 32), m, 64);
    return ((ull)(unsigned)hi << 32) | (unsigned)lo;
}
__device__ __forceinline__ void ce(ull &a, ull &b) {
    ull mn = a < b ? a : b; ull mx = a < b ? b : a; a = mn; b = mx;
}

// ---------------- kernel 1: topk(16 smallest, idx-tiebreak) + layers 1,2 + stats
__global__ __launch_bounds__(256, 4) void k1_topk_mlp(
    const float* __restrict__ theta, const float* __restrict__ dist,
    const float* __restrict__ ins,  // [2,B,N]
    const float* __restrict__ W1, const float* __restrict__ b1,
    const float* __restrict__ W2, const float* __restrict__ b2,
    float* __restrict__ ws)
{
    const int row = blockIdx.x;            // b*N+n
    const int b = row / NN, n = row % NN;
    const int t = threadIdx.x;
    const int lane = t & 63, wid = t >> 6;

    __shared__ ull  cand[64];
    __shared__ float sdv[KK]; __shared__ int sid[KK];
    __shared__ float xbuf[D_IN];
    __shared__ float h1[E1];

    // ---- load 8 dist elements straight to registers (coalesced float4) ----
    const float4* d4 = (const float4*)(dist + (size_t)row * MM);
    ull K[16];
    {
        float4 va = d4[t];                       // elements 4t..4t+3 (t<500 always)
        K[0] = ((ull)__float_as_uint(va.x) << 32) | (unsigned)(4*t + 0);
        K[1] = ((ull)__float_as_uint(va.y) << 32) | (unsigned)(4*t + 1);
        K[2] = ((ull)__float_as_uint(va.z) << 32) | (unsigned)(4*t + 2);
        K[3] = ((ull)__float_as_uint(va.w) << 32) | (unsigned)(4*t + 3);
        if (t < MM/4 - 256) {                    // t < 244
            float4 vb = d4[256 + t];             // elements 1024+4t..+3
            K[4] = ((ull)__float_as_uint(vb.x) << 32) | (unsigned)(1024 + 4*t + 0);
            K[5] = ((ull)__float_as_uint(vb.y) << 32) | (unsigned)(1024 + 4*t + 1);
            K[6] = ((ull)__float_as_uint(vb.z) << 32) | (unsigned)(1024 + 4*t + 2);
            K[7] = ((ull)__float_as_uint(vb.w) << 32) | (unsigned)(1024 + 4*t + 3);
        } else {
            K[4] = K[5] = K[6] = K[7] = ~0ull;
        }
    }

    // ---- sort the 8 keys (Batcher odd-even mergesort, 19 CE) ----
    ce(K[0],K[1]); ce(K[2],K[3]); ce(K[4],K[5]); ce(K[6],K[7]);
    ce(K[0],K[2]); ce(K[1],K[3]); ce(K[4],K[6]); ce(K[5],K[7]);
    ce(K[1],K[2]); ce(K[5],K[6]);
    ce(K[0],K[4]); ce(K[1],K[5]); ce(K[2],K[6]); ce(K[3],K[7]);
    ce(K[2],K[4]); ce(K[3],K[5]);
    ce(K[1],K[2]); ce(K[3],K[4]); ce(K[5],K[6]);

    // ---- merge step d=1: my sorted 8 ++ reverse(partner 8) -> sorted 16 ----
    {
        ull M[16];
        #pragma unroll
        for (int i = 0; i < 8; ++i)  M[i] = K[i];
        #pragma unroll
        for (int i = 8; i < 16; ++i) M[i] = shflx64(K[15 - i], 1);
        #pragma unroll
        for (int s = 8; s > 0; s >>= 1) {
            #pragma unroll
            for (int i = 0; i < 16; ++i)
                if ((i & s) == 0) ce(M[i], M[i + s]);
        }
        #pragma unroll
        for (int i = 0; i < 16; ++i) K[i] = M[i];
    }

    // ---- merge steps d=2..32: keep smallest 16 of (mine ∪ partner) -------
    #pragma unroll
    for (int d = 2; d <= 32; d <<= 1) {
        ull M[16];
        #pragma unroll
        for (int i = 0; i < 16; ++i) {
            ull o = shflx64(K[15 - i], d);
            M[i] = K[i] < o ? K[i] : o;       // lower half of bitonic merge
        }
        #pragma unroll
        for (int s = 8; s > 0; s >>= 1) {
            #pragma unroll
            for (int i = 0; i < 16; ++i)
                if ((i & s) == 0) ce(M[i], M[i + s]);
        }
        #pragma unroll
        for (int i = 0; i < 16; ++i) K[i] = M[i];
    }
    // every lane now holds its wave's top-16 (sorted)

    if (lane == 0) {
        #pragma unroll
        for (int i = 0; i < 16; ++i) cand[wid*16 + i] = K[i];
    }
    __syncthreads();

    // ---- final: 64-lane bitonic sort of the 4 wave lists -------------------
    if (t < 64) {
        ull key = cand[t];
        #pragma unroll
        for (int kk = 2; kk <= 64; kk <<= 1) {
            #pragma unroll
            for (int j = kk >> 1; j > 0; j >>= 1) {
                ull o = shflx64(key, j);
                bool keepMin = ((t & j) == 0) == ((t & kk) == 0);
                if (keepMin ? (o < key) : (o > key)) key = o;
            }
        }
        if (t < KK) {
            sdv[t] = __uint_as_float((unsigned)(key >> 32));
            sid[t] = (int)(key & 0xFFFFFFFFu);
        }
    }
    __syncthreads();

    // ---- normalize sorted_dist, gather theta, build x ---------------------
    const float dmax = sdv[KK-1];
    if (t < KK) {
        float nd = sdv[t] / dmax;
        int   id = sid[t];
        xbuf[t]        = nd;
        xbuf[KK + t]   = theta[(size_t)row * MM + id];
        ws[OFF_SD + (size_t)row*KK + t] = nd;
        ((int*)(ws + OFF_SI))[(size_t)row*KK + t] = id;
    }
    if (t == 0) {
        xbuf[2*KK]     = ins[(size_t)b*NN + n];
        xbuf[2*KK + 1] = ins[(size_t)BB*NN + (size_t)b*NN + n];
    }
    __syncthreads();

    // ---- layer 1: 34 -> 128, relu (W1 row per thread, float2) -------------
    if (t < E1) {
        const float2* wp = (const float2*)(W1 + (size_t)t * D_IN); // 136B, 8B-aligned
        float acc = b1[t];
        #pragma unroll
        for (int j = 0; j < D_IN/2; ++j) {
            float2 wv = wp[j];
            acc += wv.x * xbuf[2*j] + wv.y * xbuf[2*j + 1];
        }
        h1[t] = fmaxf(acc, 0.0f);
    }
    __syncthreads();

    // ---- layer 2: 128 -> 256, relu; store h2 + stats atomics --------------
    {
        const float4* wp  = (const float4*)(W2 + (size_t)t * E1);  // 512B rows
        const float4* h14 = (const float4*)h1;
        float acc = b2[t];
        #pragma unroll 8
        for (int j = 0; j < E1/4; ++j) {
            float4 a = h14[j]; float4 w = wp[j];
            acc += a.x*w.x + a.y*w.y + a.z*w.z + a.w*w.w;
        }
        float v = fmaxf(acc, 0.0f);
        ws[OFF_H2 + (size_t)row*E2 + t] = v;
        atomicAdd(&ws[OFF_ST + (size_t)b*E2 + t], v);
        atomicAdd(&ws[OFF_ST + (size_t)BB*E2 + (size_t)b*E2 + t], v*v);
    }
}

// ---------------- kernel 3: norm + layers 3,4 + fill + scatter (8 rows/block)
__global__ __launch_bounds__(256) void k3_norm_out(
    const float* __restrict__ W3, const float* __restrict__ b3,
    const float* __restrict__ W4, const float* __restrict__ b4,
    const float* __restrict__ gamma, const float* __restrict__ beta,
    const float* __restrict__ ws, float* __restrict__ out)
{
    const int row0 = blockIdx.x * RT;      // NN%RT==0 -> all rows share batch b
    const int b = row0 / NN;
    const int t = threadIdx.x;

    __shared__ float hn[RT][E2];           // 8 KB
    __shared__ float h3s[RT][E1];          // 4 KB
    __shared__ float p4[2][128];
    __shared__ float o16[RT][KK];
    __shared__ float sds[RT][KK];
    __shared__ int   sis[RT][KK];

    // normalize 8 rows of h2 (biased variance, eps inside sqrt)
    {
        float s1 = ws[OFF_ST + (size_t)b*E2 + t];
        float s2 = ws[OFF_ST + (size_t)BB*E2 + (size_t)b*E2 + t];
        float mu  = s1 / (float)NN;
        float var = s2 / (float)NN - mu*mu;
        float inv = 1.0f / sqrtf(var + EPSV);
        float ga = gamma[t], be = beta[t];
        #pragma unroll
        for (int r = 0; r < RT; ++r) {
            float v = ws[OFF_H2 + (size_t)(row0 + r)*E2 + t];
            hn[r][t] = (v - mu) * inv * ga + be;
        }
    }
    if (t < RT*KK) {
        sds[t>>4][t&15] = ws[OFF_SD + (size_t)row0*KK + t];
        sis[t>>4][t&15] = ((const int*)(ws + OFF_SI))[(size_t)row0*KK + t];
    }
    __syncthreads();

    // layer 3: 256 -> 128 for 8 rows. thread = (channel c, row-group g of 4)
    {
        const int c = t & (E1-1), g = t >> 7;
        const float4* wp = (const float4*)(W3 + (size_t)c * E2);
        const float4* a0 = (const float4*)hn[4*g+0];
        const float4* a1 = (const float4*)hn[4*g+1];
        const float4* a2 = (const float4*)hn[4*g+2];
        const float4* a3 = (const float4*)hn[4*g+3];
        float acc0=0.f, acc1=0.f, acc2=0.f, acc3=0.f;
        #pragma unroll 8
        for (int j = 0; j < E2/4; ++j) {
            float4 w = wp[j];
            float4 x0 = a0[j]; acc0 += w.x*x0.x + w.y*x0.y + w.z*x0.z + w.w*x0.w;
            float4 x1 = a1[j]; acc1 += w.x*x1.x + w.y*x1.y + w.z*x1.z + w.w*x1.w;
            float4 x2 = a2[j]; acc2 += w.x*x2.x + w.y*x2.y + w.z*x2.z + w.w*x2.w;
            float4 x3 = a3[j]; acc3 += w.x*x3.x + w.y*x3.y + w.z*x3.z + w.w*x3.w;
        }
        float bb = b3[c];
        h3s[4*g+0][c] = fmaxf(acc0 + bb, 0.f);
        h3s[4*g+1][c] = fmaxf(acc1 + bb, 0.f);
        h3s[4*g+2][c] = fmaxf(acc2 + bb, 0.f);
        h3s[4*g+3][c] = fmaxf(acc3 + bb, 0.f);
    }
    __syncthreads();

    // layer 4: 128 outputs (8 rows x 16), 2 K-halves per output
    {
        const int idx = t >> 1, half = t & 1;
        const int r = idx >> 4, oc = idx & 15;
        const float4* wp = (const float4*)(W4 + (size_t)oc * E1 + half*64);
        const float4* hh = (const float4*)h3s[r] + half*16;
        float acc = 0.f;
        #pragma unroll
        for (int j = 0; j < 16; ++j) {
            float4 w = wp[j]; float4 x = hh[j];
            acc += w.x*x.x + w.y*x.y + w.z*x.z + w.w*x.w;
        }
        p4[half][idx] = acc;
    }
    __syncthreads();
    if (t < 128) {
        const int r = t >> 4, oc = t & 15;
        o16[r][oc] = p4[0][t] + p4[1][t] + b4[oc] - sds[r][oc];
    }
    __syncthreads();

    // fill 8 rows with PENALTY (float4), then scatter the 128 outputs
    {
        const float4 pv = make_float4(PEN, PEN, PEN, PEN);
        #pragma unroll
        for (int r = 0; r < RT; ++r) {
            float4* o4 = (float4*)(out + (size_t)(row0 + r) * MM);
            for (int i = t; i < MM/4; i += 256) o4[i] = pv;
        }
    }
    __syncthreads();
    if (t < 128) {
        const int r = t >> 4, oc = t & 15;
        out[(size_t)(row0 + r) * MM + sis[r][oc]] = o16[r][oc];
    }
}

extern "C" void kernel_launch(void* const* d_in, const int* in_sizes, int n_in,
                              void* d_out, int out_size, void* d_ws, size_t ws_size,
                              hipStream_t stream) {
    const float* theta = (const float*)d_in[0];
    const float* dist  = (const float*)d_in[1];
    const float* ins   = (const float*)d_in[2];
    const float* W1 = (const float*)d_in[3];
    const float* b1 = (const float*)d_in[4];
    const float* W2 = (const float*)d_in[5];
    const float* b2 = (const float*)d_in[6];
    const float* W3 = (const float*)d_in[7];
    const float* b3 = (const float*)d_in[8];
    const float* W4 = (const float*)d_in[9];
    const float* b4 = (const float*)d_in[10];
    const float* gamma = (const float*)d_in[11];
    const float* beta  = (const float*)d_in[12];
    float* ws  = (float*)d_ws;
    float* out = (float*)d_out;

    // zero the stats accumulators (ws is poisoned 0xAA before every launch)
    hipMemsetAsync(ws + OFF_ST, 0, (size_t)2*BB*E2*sizeof(float), stream);

    k1_topk_mlp<<<ROWS, 256, 0, stream>>>(theta, dist, ins, W1, b1, W2, b2, ws);
    k3_norm_out<<<ROWS/RT, 256, 0, stream>>>(W3, b3, W4, b4, gamma, beta, ws, out);
}

// Round 5
// 340.270 us; speedup vs baseline: 1.2453x; 1.1481x over previous
//
#include <hip/hip_runtime.h>
#include <cfloat>

// Problem constants (match setup_inputs)
#define BB 4
#define NN 2000
#define MM 2000
#define KK 16
#define D_IN 34      // 2K+2
#define E1 128
#define E2 256
#define PEN -10.0f
#define EPSV 1e-5f
#define ROWS (BB*NN) // 8000
#define RT3 16       // rows per block in k3

// ws float-offsets
#define OFF_H2  ((size_t)0)                         // ROWS*E2 floats
#define OFF_SD  (OFF_H2 + (size_t)ROWS*E2)          // ROWS*KK floats
#define OFF_SI  (OFF_SD + (size_t)ROWS*KK)          // ROWS*KK ints
#define OFF_ST  (OFF_SI + (size_t)ROWS*KK)          // 2*BB*E2 floats (sum, sumsq)
#define OFF_W1T (OFF_ST + (size_t)2*BB*E2)          // D_IN*E1
#define OFF_W2T (OFF_W1T + (size_t)D_IN*E1)         // E1*E2   [k][c]
#define OFF_W3T (OFF_W2T + (size_t)E1*E2)           // E2*E1   [k][c]
#define OFF_W4T (OFF_W3T + (size_t)E2*E1)           // E1*KK   [k][c]

typedef unsigned long long ull;

__device__ __forceinline__ ull shflx64(ull v, int m) {
    int lo = __shfl_xor((int)(unsigned)(v & 0xffffffffull), m, 64);
    int hi = __shfl_xor((int)(unsigned)(v >> 32), m, 64);
    return ((ull)(unsigned)hi << 32) | (unsigned)lo;
}

// ---------------- weight transposes (one tiny kernel) ----------------------
__global__ void k_prep(const float* __restrict__ W1, const float* __restrict__ W2,
                       const float* __restrict__ W3, const float* __restrict__ W4,
                       float* __restrict__ ws) {
    int i = blockIdx.x * 256 + threadIdx.x;
    if (i < D_IN*E1) { int k = i / E1, c = i % E1; ws[OFF_W1T + i] = W1[c*D_IN + k]; return; }
    i -= D_IN*E1;
    if (i < E1*E2) { int k = i / E2, c = i % E2; ws[OFF_W2T + (size_t)k*E2 + c] = W2[c*E1 + k]; return; }
    i -= E1*E2;
    if (i < E2*E1) { int k = i / E1, c = i % E1; ws[OFF_W3T + (size_t)k*E1 + c] = W3[c*E2 + k]; return; }
    i -= E2*E1;
    if (i < E1*KK) { int k = i / KK, c = i % KK; ws[OFF_W4T + (size_t)k*KK + c] = W4[c*E1 + k]; }
}

// ---- kernel 1: topk(16 smallest, idx-tiebreak) + layers 1,2 + stats + fill
__global__ __launch_bounds__(256) void k1_topk_mlp(
    const float* __restrict__ theta, const float* __restrict__ dist,
    const float* __restrict__ ins,  // [2,B,N]
    const float* __restrict__ b1, const float* __restrict__ b2,
    float* __restrict__ ws, float* __restrict__ out)
{
    const int row = blockIdx.x;            // b*N+n
    const int b = row / NN, n = row % NN;
    const int t = threadIdx.x;
    const int lane = t & 63, wid = t >> 6;

    __shared__ float vals[MM];             // used only by the exact fallback
    __shared__ float gm[64];
    __shared__ ull  cand[64];
    __shared__ int s_cnt;
    __shared__ unsigned s_tb;
    __shared__ float redv[4]; __shared__ int redi[4];
    __shared__ float sdv[KK]; __shared__ int sid[KK];
    __shared__ float xbuf[D_IN];
    __shared__ float h1[E1];

    // ---- load 8 dist elements to registers (coalesced float4) -------------
    const float4* d4 = (const float4*)(dist + (size_t)row * MM);
    float4 va = d4[t];                         // elems 4t..4t+3  (t < 500)
    const bool hasB = (t < MM/4 - 256);        // t < 244
    float4 vb = hasB ? d4[256 + t]
                     : make_float4(FLT_MAX, FLT_MAX, FLT_MAX, FLT_MAX);
    if (t == 0) s_cnt = 0;

    // ---- per-thread min, then 4-lane group min ----------------------------
    float m = fminf(fminf(va.x, va.y), fminf(va.z, va.w));
    m = fminf(m, fminf(fminf(vb.x, vb.y), fminf(vb.z, vb.w)));
    m = fminf(m, __shfl_xor(m, 1));
    m = fminf(m, __shfl_xor(m, 2));
    if ((lane & 3) == 0) gm[t >> 2] = m;
    __syncthreads();

    // ---- wave 0: sort the 64 group minima; T = 16th smallest --------------
    // (16 smallest group-minima are 16 distinct elements <= T, so the set
    //  {x <= T} is a superset of the exact top-16.)
    if (t < 64) {
        unsigned key = __float_as_uint(gm[t]);
        #pragma unroll
        for (int kk = 2; kk <= 64; kk <<= 1) {
            #pragma unroll
            for (int j = kk >> 1; j > 0; j >>= 1) {
                unsigned o = __shfl_xor(key, j);
                bool keepMin = ((t & j) == 0) == ((t & kk) == 0);
                if (keepMin ? (o < key) : (o > key)) key = o;
            }
        }
        if (t == 15) s_tb = key;               // ascending -> lane 15 = 16th
    }
    __syncthreads();
    const unsigned tb = s_tb;

    // ---- compact candidates (expected ~18, guaranteed >= 16) --------------
    {
        unsigned bx;
        bx = __float_as_uint(va.x); if (bx <= tb) { int p = atomicAdd(&s_cnt,1); if (p<64) cand[p] = ((ull)bx<<32) | (unsigned)(4*t+0); }
        bx = __float_as_uint(va.y); if (bx <= tb) { int p = atomicAdd(&s_cnt,1); if (p<64) cand[p] = ((ull)bx<<32) | (unsigned)(4*t+1); }
        bx = __float_as_uint(va.z); if (bx <= tb) { int p = atomicAdd(&s_cnt,1); if (p<64) cand[p] = ((ull)bx<<32) | (unsigned)(4*t+2); }
        bx = __float_as_uint(va.w); if (bx <= tb) { int p = atomicAdd(&s_cnt,1); if (p<64) cand[p] = ((ull)bx<<32) | (unsigned)(4*t+3); }
        if (hasB) {
            bx = __float_as_uint(vb.x); if (bx <= tb) { int p = atomicAdd(&s_cnt,1); if (p<64) cand[p] = ((ull)bx<<32) | (unsigned)(1024+4*t+0); }
            bx = __float_as_uint(vb.y); if (bx <= tb) { int p = atomicAdd(&s_cnt,1); if (p<64) cand[p] = ((ull)bx<<32) | (unsigned)(1024+4*t+1); }
            bx = __float_as_uint(vb.z); if (bx <= tb) { int p = atomicAdd(&s_cnt,1); if (p<64) cand[p] = ((ull)bx<<32) | (unsigned)(1024+4*t+2); }
            bx = __float_as_uint(vb.w); if (bx <= tb) { int p = atomicAdd(&s_cnt,1); if (p<64) cand[p] = ((ull)bx<<32) | (unsigned)(1024+4*t+3); }
        }
    }
    __syncthreads();
    const int cnt = s_cnt;                     // block-uniform

    if (cnt <= 64) {
        // exact: 64-key bitonic sort of (valbits, idx)
        if (t < 64) {
            ull key = (t < cnt) ? cand[t] : ~0ull;
            #pragma unroll
            for (int kk = 2; kk <= 64; kk <<= 1) {
                #pragma unroll
                for (int j = kk >> 1; j > 0; j >>= 1) {
                    ull o = shflx64(key, j);
                    bool keepMin = ((t & j) == 0) == ((t & kk) == 0);
                    if (keepMin ? (o < key) : (o > key)) key = o;
                }
            }
            if (t < KK) {
                sdv[t] = __uint_as_float((unsigned)(key >> 32));
                sid[t] = (int)(key & 0xFFFFFFFFu);
            }
        }
    } else {
        // exact fallback (astronomically rare): stage row, 16-pass argmin
        vals[4*t+0] = va.x; vals[4*t+1] = va.y; vals[4*t+2] = va.z; vals[4*t+3] = va.w;
        if (hasB) { vals[1024+4*t+0] = vb.x; vals[1024+4*t+1] = vb.y;
                    vals[1024+4*t+2] = vb.z; vals[1024+4*t+3] = vb.w; }
        __syncthreads();
        for (int it = 0; it < KK; ++it) {
            float mv = FLT_MAX; int mi = -1;
            for (int i = t; i < MM; i += 256) {
                float vv = vals[i];
                if (vv < mv || (vv == mv && i < mi)) { mv = vv; mi = i; }
            }
            #pragma unroll
            for (int off = 32; off; off >>= 1) {
                float ov = __shfl_down(mv, off);
                int   oi = __shfl_down(mi, off);
                if (ov < mv || (ov == mv && oi < mi)) { mv = ov; mi = oi; }
            }
            if (lane == 0) { redv[wid] = mv; redi[wid] = mi; }
            __syncthreads();
            if (t == 0) {
                mv = redv[0]; mi = redi[0];
                #pragma unroll
                for (int w = 1; w < 4; ++w) {
                    float ov = redv[w]; int oi = redi[w];
                    if (ov < mv || (ov == mv && oi < mi)) { mv = ov; mi = oi; }
                }
                sdv[it] = mv; sid[it] = mi;
                vals[mi] = FLT_MAX;
            }
            __syncthreads();
        }
    }
    __syncthreads();

    // ---- penalty-fill this block's output row (overlaps with what follows)
    float* orow = out + (size_t)row * MM;
    {
        float4* o4 = (float4*)orow;
        const float4 pv = make_float4(PEN, PEN, PEN, PEN);
        o4[t] = pv;                            // t < 500 always
        if (t < MM/4 - 256) o4[256 + t] = pv;
    }

    // ---- normalize sorted_dist, gather theta, build x ---------------------
    const float dmax = sdv[KK-1];
    if (t < KK) {
        float nd = sdv[t] / dmax;
        int   id = sid[t];
        xbuf[t]        = nd;
        xbuf[KK + t]   = theta[(size_t)row * MM + id];
        ws[OFF_SD + (size_t)row*KK + t] = nd;
        ((int*)(ws + OFF_SI))[(size_t)row*KK + t] = id;
    }
    if (t == 0) {
        xbuf[2*KK]     = ins[(size_t)b*NN + n];
        xbuf[2*KK + 1] = ins[(size_t)BB*NN + (size_t)b*NN + n];
    }
    __syncthreads();

    // ---- layer 1: 34 -> 128, relu (W1T coalesced) -------------------------
    if (t < E1) {
        float acc = b1[t];
        #pragma unroll
        for (int k = 0; k < D_IN; ++k) acc += xbuf[k] * ws[OFF_W1T + (size_t)k*E1 + t];
        h1[t] = fmaxf(acc, 0.0f);
    }
    __syncthreads();

    // ---- layer 2: 128 -> 256, relu (W2T coalesced); store h2 + stats ------
    {
        float acc = b2[t];
        #pragma unroll 8
        for (int k = 0; k < E1; ++k) acc += h1[k] * ws[OFF_W2T + (size_t)k*E2 + t];
        float v = fmaxf(acc, 0.0f);
        ws[OFF_H2 + (size_t)row*E2 + t] = v;
        atomicAdd(&ws[OFF_ST + (size_t)b*E2 + t], v);
        atomicAdd(&ws[OFF_ST + (size_t)BB*E2 + (size_t)b*E2 + t], v*v);
    }
}

// ---- kernel 3: norm + layers 3,4 + scatter (16 rows/block, 500 blocks) ----
__global__ __launch_bounds__(256) void k3_norm_out(
    const float* __restrict__ b3, const float* __restrict__ b4,
    const float* __restrict__ gamma, const float* __restrict__ beta,
    const float* __restrict__ ws, float* __restrict__ out)
{
    const int row0 = blockIdx.x * RT3;     // 2000 % 16 == 0 -> single batch b
    const int b = row0 / NN;
    const int t = threadIdx.x;

    __shared__ float hn[RT3][E2 + 1];      // stride 257 -> conflict-free [r][k]
    __shared__ float h3s[RT3][E1 + 4];     // stride 132 -> conflict-free + 16B-aligned
    __shared__ float sds[RT3][KK];
    __shared__ int   sis[RT3][KK];

    // normalize 16 rows of h2 (biased variance, eps inside sqrt)
    {
        float s1 = ws[OFF_ST + (size_t)b*E2 + t];
        float s2 = ws[OFF_ST + (size_t)BB*E2 + (size_t)b*E2 + t];
        float mu  = s1 / (float)NN;
        float var = s2 / (float)NN - mu*mu;
        float inv = 1.0f / sqrtf(var + EPSV);
        float ga = gamma[t], be = beta[t];
        #pragma unroll
        for (int r = 0; r < RT3; ++r) {
            float v = ws[OFF_H2 + (size_t)(row0 + r)*E2 + t];   // coalesced
            hn[r][t] = (v - mu) * inv * ga + be;
        }
    }
    {
        const int r = t >> 4, oc = t & 15;
        sds[r][oc] = ws[OFF_SD + (size_t)(row0 + r)*KK + oc];
        sis[r][oc] = ((const int*)(ws + OFF_SI))[(size_t)(row0 + r)*KK + oc];
    }
    __syncthreads();

    // layer 3: 256 -> 128 for 16 rows.
    // thread = (row r = t&15, quad-pair qp = t>>4): channels 4qp..4qp+3 and 64+4qp..
    {
        const int r = t & 15, qp = t >> 4;
        const float4* w3t4 = (const float4*)(ws + OFF_W3T);
        float4 acc0 = make_float4(0.f,0.f,0.f,0.f);
        float4 acc1 = make_float4(0.f,0.f,0.f,0.f);
        #pragma unroll 8
        for (int k = 0; k < E2; ++k) {
            float hv  = hn[r][k];                       // 16 rows -> 16 banks, no conflict
            float4 w0 = w3t4[(size_t)k*32 + qp];        // W3T[k][4qp..]
            float4 w1 = w3t4[(size_t)k*32 + 16 + qp];   // W3T[k][64+4qp..]
            acc0.x += hv*w0.x; acc0.y += hv*w0.y; acc0.z += hv*w0.z; acc0.w += hv*w0.w;
            acc1.x += hv*w1.x; acc1.y += hv*w1.y; acc1.z += hv*w1.z; acc1.w += hv*w1.w;
        }
        const int c0 = qp*4, c1 = 64 + qp*4;
        h3s[r][c0+0] = fmaxf(acc0.x + b3[c0+0], 0.f);
        h3s[r][c0+1] = fmaxf(acc0.y + b3[c0+1], 0.f);
        h3s[r][c0+2] = fmaxf(acc0.z + b3[c0+2], 0.f);
        h3s[r][c0+3] = fmaxf(acc0.w + b3[c0+3], 0.f);
        h3s[r][c1+0] = fmaxf(acc1.x + b3[c1+0], 0.f);
        h3s[r][c1+1] = fmaxf(acc1.y + b3[c1+1], 0.f);
        h3s[r][c1+2] = fmaxf(acc1.z + b3[c1+2], 0.f);
        h3s[r][c1+3] = fmaxf(acc1.w + b3[c1+3], 0.f);
    }
    __syncthreads();

    // layer 4: 128 -> 16 for 16 rows; write scattered outputs directly.
    // thread = (row r = t>>4, output oc = t&15)
    {
        const int r = t >> 4, oc = t & 15;
        const float* w4t = ws + OFF_W4T;
        float acc = b4[oc];
        #pragma unroll 8
        for (int k = 0; k < E1; ++k)
            acc += h3s[r][k] * w4t[(size_t)k*KK + oc];  // h3s broadcast; w coalesced
        out[(size_t)(row0 + r) * MM + sis[r][oc]] = acc - sds[r][oc];
    }
}

extern "C" void kernel_launch(void* const* d_in, const int* in_sizes, int n_in,
                              void* d_out, int out_size, void* d_ws, size_t ws_size,
                              hipStream_t stream) {
    const float* theta = (const float*)d_in[0];
    const float* dist  = (const float*)d_in[1];
    const float* ins   = (const float*)d_in[2];
    const float* W1 = (const float*)d_in[3];
    const float* b1 = (const float*)d_in[4];
    const float* W2 = (const float*)d_in[5];
    const float* b2 = (const float*)d_in[6];
    const float* W3 = (const float*)d_in[7];
    const float* b3 = (const float*)d_in[8];
    const float* W4 = (const float*)d_in[9];
    const float* b4 = (const float*)d_in[10];
    const float* gamma = (const float*)d_in[11];
    const float* beta  = (const float*)d_in[12];
    float* ws  = (float*)d_ws;
    float* out = (float*)d_out;

    // zero the stats accumulators (ws is poisoned 0xAA before every launch)
    hipMemsetAsync(ws + OFF_ST, 0, (size_t)2*BB*E2*sizeof(float), stream);

    {
        int total = D_IN*E1 + E1*E2 + E2*E1 + E1*KK;
        k_prep<<<(total + 255)/256, 256, 0, stream>>>(W1, W2, W3, W4, ws);
    }
    k1_topk_mlp<<<ROWS, 256, 0, stream>>>(theta, dist, ins, b1, b2, ws, out);
    k3_norm_out<<<ROWS/RT3, 256, 0, stream>>>(b3, b4, gamma, beta, ws, out);
}

// Round 6
// 236.168 us; speedup vs baseline: 1.7942x; 1.4408x over previous
//
#include <hip/hip_runtime.h>
#include <cfloat>

// Problem constants (match setup_inputs)
#define BB 4
#define NN 2000
#define MM 2000
#define KK 16
#define D_IN 34      // 2K+2
#define E1 128
#define E2 256
#define PEN -10.0f
#define EPSV 1e-5f
#define ROWS (BB*NN) // 8000
#define RB 20        // rows per block in kB/kC (2000 % 20 == 0 -> uniform batch)
#define XS 36        // x row stride (16 nd + 16 theta + 2 ins + 2 pad)

// ws float-offsets
#define OFF_H2  ((size_t)0)                          // ROWS*E2   = 2,048,000
#define OFF_X   (OFF_H2 + (size_t)ROWS*E2)           // ROWS*XS   =   288,000
#define OFF_SI  (OFF_X  + (size_t)ROWS*XS)           // ROWS*KK ints
#define OFF_ST  (OFF_SI + (size_t)ROWS*KK)           // 2*BB*E2 (sum, sumsq)
#define OFF_W2T (OFF_ST + (size_t)2*BB*E2)           // [k=128][c=256]
#define OFF_W3T (OFF_W2T + (size_t)E1*E2)            // [k=256][c=128]
#define OFF_W4T (OFF_W3T + (size_t)E2*E1)            // [k=128][oc=16]

typedef unsigned long long ull;

__device__ __forceinline__ ull shflx64(ull v, int m) {
    int lo = __shfl_xor((int)(unsigned)(v & 0xffffffffull), m, 64);
    int hi = __shfl_xor((int)(unsigned)(v >> 32), m, 64);
    return ((ull)(unsigned)hi << 32) | (unsigned)lo;
}

// ---------------- weight transposes ----------------------------------------
__global__ void k_prep(const float* __restrict__ W2, const float* __restrict__ W3,
                       const float* __restrict__ W4, float* __restrict__ ws) {
    int i = blockIdx.x * 256 + threadIdx.x;
    if (i < E1*E2) { int k = i >> 8, c = i & 255; ws[OFF_W2T + i] = W2[c*E1 + k]; return; }
    i -= E1*E2;
    if (i < E2*E1) { int k = i >> 7, c = i & 127; ws[OFF_W3T + i] = W3[c*E2 + k]; return; }
    i -= E2*E1;
    if (i < E1*KK) { int k = i >> 4, oc = i & 15; ws[OFF_W4T + i] = W4[oc*E1 + k]; }
}

// ---- kA: per-row top-16 (threshold + exact bitonic, idx tiebreak) + x build
__global__ __launch_bounds__(256) void kA_select(
    const float* __restrict__ theta, const float* __restrict__ dist,
    const float* __restrict__ ins, float* __restrict__ ws)
{
    const int row = blockIdx.x;            // b*N+n
    const int b = row / NN, n = row % NN;
    const int t = threadIdx.x;
    const int lane = t & 63, wid = t >> 6;

    __shared__ float vals[MM];             // only used by the exact fallback
    __shared__ float gm[64];
    __shared__ ull  cand[64];
    __shared__ int s_cnt;
    __shared__ unsigned s_tb;
    __shared__ float redv[4]; __shared__ int redi[4];
    __shared__ float sdv[KK]; __shared__ int sid[KK];

    const float4* d4 = (const float4*)(dist + (size_t)row * MM);
    float4 va = d4[t];                         // elems 4t..4t+3 (t < 500)
    const bool hasB = (t < MM/4 - 256);        // t < 244
    float4 vb = hasB ? d4[256 + t]
                     : make_float4(FLT_MAX, FLT_MAX, FLT_MAX, FLT_MAX);
    if (t == 0) s_cnt = 0;

    // per-thread min, then 4-lane group min
    float m = fminf(fminf(va.x, va.y), fminf(va.z, va.w));
    m = fminf(m, fminf(fminf(vb.x, vb.y), fminf(vb.z, vb.w)));
    m = fminf(m, __shfl_xor(m, 1));
    m = fminf(m, __shfl_xor(m, 2));
    if ((lane & 3) == 0) gm[t >> 2] = m;
    __syncthreads();

    // wave 0: sort 64 group minima; T = 16th smallest (superset guarantee)
    if (t < 64) {
        unsigned key = __float_as_uint(gm[t]);
        #pragma unroll
        for (int kk = 2; kk <= 64; kk <<= 1) {
            #pragma unroll
            for (int j = kk >> 1; j > 0; j >>= 1) {
                unsigned o = __shfl_xor(key, j);
                bool keepMin = ((t & j) == 0) == ((t & kk) == 0);
                if (keepMin ? (o < key) : (o > key)) key = o;
            }
        }
        if (t == 15) s_tb = key;
    }
    __syncthreads();
    const unsigned tb = s_tb;

    // compact candidates (expected ~18, guaranteed >= 16)
    {
        unsigned bx;
        bx = __float_as_uint(va.x); if (bx <= tb) { int p = atomicAdd(&s_cnt,1); if (p<64) cand[p] = ((ull)bx<<32) | (unsigned)(4*t+0); }
        bx = __float_as_uint(va.y); if (bx <= tb) { int p = atomicAdd(&s_cnt,1); if (p<64) cand[p] = ((ull)bx<<32) | (unsigned)(4*t+1); }
        bx = __float_as_uint(va.z); if (bx <= tb) { int p = atomicAdd(&s_cnt,1); if (p<64) cand[p] = ((ull)bx<<32) | (unsigned)(4*t+2); }
        bx = __float_as_uint(va.w); if (bx <= tb) { int p = atomicAdd(&s_cnt,1); if (p<64) cand[p] = ((ull)bx<<32) | (unsigned)(4*t+3); }
        if (hasB) {
            bx = __float_as_uint(vb.x); if (bx <= tb) { int p = atomicAdd(&s_cnt,1); if (p<64) cand[p] = ((ull)bx<<32) | (unsigned)(1024+4*t+0); }
            bx = __float_as_uint(vb.y); if (bx <= tb) { int p = atomicAdd(&s_cnt,1); if (p<64) cand[p] = ((ull)bx<<32) | (unsigned)(1024+4*t+1); }
            bx = __float_as_uint(vb.z); if (bx <= tb) { int p = atomicAdd(&s_cnt,1); if (p<64) cand[p] = ((ull)bx<<32) | (unsigned)(1024+4*t+2); }
            bx = __float_as_uint(vb.w); if (bx <= tb) { int p = atomicAdd(&s_cnt,1); if (p<64) cand[p] = ((ull)bx<<32) | (unsigned)(1024+4*t+3); }
        }
    }
    __syncthreads();
    const int cnt = s_cnt;

    if (cnt <= 64) {
        if (t < 64) {
            ull key = (t < cnt) ? cand[t] : ~0ull;
            #pragma unroll
            for (int kk = 2; kk <= 64; kk <<= 1) {
                #pragma unroll
                for (int j = kk >> 1; j > 0; j >>= 1) {
                    ull o = shflx64(key, j);
                    bool keepMin = ((t & j) == 0) == ((t & kk) == 0);
                    if (keepMin ? (o < key) : (o > key)) key = o;
                }
            }
            if (t < KK) {
                sdv[t] = __uint_as_float((unsigned)(key >> 32));
                sid[t] = (int)(key & 0xFFFFFFFFu);
            }
        }
    } else {
        // exact fallback: stage row, 16-pass argmin
        vals[4*t+0] = va.x; vals[4*t+1] = va.y; vals[4*t+2] = va.z; vals[4*t+3] = va.w;
        if (hasB) { vals[1024+4*t+0] = vb.x; vals[1024+4*t+1] = vb.y;
                    vals[1024+4*t+2] = vb.z; vals[1024+4*t+3] = vb.w; }
        __syncthreads();
        for (int it = 0; it < KK; ++it) {
            float mv = FLT_MAX; int mi = -1;
            for (int i = t; i < MM; i += 256) {
                float vv = vals[i];
                if (vv < mv || (vv == mv && i < mi)) { mv = vv; mi = i; }
            }
            #pragma unroll
            for (int off = 32; off; off >>= 1) {
                float ov = __shfl_down(mv, off);
                int   oi = __shfl_down(mi, off);
                if (ov < mv || (ov == mv && oi < mi)) { mv = ov; mi = oi; }
            }
            if (lane == 0) { redv[wid] = mv; redi[wid] = mi; }
            __syncthreads();
            if (t == 0) {
                mv = redv[0]; mi = redi[0];
                #pragma unroll
                for (int w = 1; w < 4; ++w) {
                    float ov = redv[w]; int oi = redi[w];
                    if (ov < mv || (ov == mv && oi < mi)) { mv = ov; mi = oi; }
                }
                sdv[it] = mv; sid[it] = mi;
                vals[mi] = FLT_MAX;
            }
            __syncthreads();
        }
    }
    __syncthreads();

    // write x row: [0..15]=nd, [16..31]=theta, [32..33]=ins, [34..35]=0
    const float dmax = sdv[KK-1];
    float* xr = ws + OFF_X + (size_t)row * XS;
    if (t < KK) {
        int id = sid[t];
        xr[t]      = sdv[t] / dmax;
        xr[KK + t] = theta[(size_t)row * MM + id];
        ((int*)(ws + OFF_SI))[(size_t)row*KK + t] = id;
    }
    if (t == 0) {
        xr[32] = ins[(size_t)b*NN + n];
        xr[33] = ins[(size_t)BB*NN + (size_t)b*NN + n];
        xr[34] = 0.f; xr[35] = 0.f;
    }
}

// ---- kB: layers 1,2 for 20 rows/block + per-batch stats atomics -----------
__global__ __launch_bounds__(256) void kB_mlp12(
    const float* __restrict__ W1, const float* __restrict__ b1,
    const float* __restrict__ b2, float* __restrict__ ws)
{
    const int row0 = blockIdx.x * RB;      // 2000%20==0 -> uniform batch
    const int b = row0 / NN;
    const int t = threadIdx.x;

    __shared__ float xs[RB * XS];          // 2.9 KB
    __shared__ float w1t[D_IN * E1];       // 17.4 KB, [k][c]
    __shared__ float h1s[RB * 130];        // 10.4 KB, stride 130 (8B-aligned f2)
    __shared__ float ls1[E2], ls2[E2];

    // stage x (float4, coalesced)
    {
        const float4* xg = (const float4*)(ws + OFF_X + (size_t)row0 * XS);
        float4* xs4 = (float4*)xs;
        for (int i = t; i < RB*XS/4; i += 256) xs4[i] = xg[i];
    }
    // stage W1 transposed into LDS: w1t[k][c] = W1[c][k]
    for (int i = t; i < D_IN*E1; i += 256) {
        int c = i / D_IN, k = i % D_IN;
        w1t[k*E1 + c] = W1[i];
    }
    ls1[t] = 0.f; ls2[t] = 0.f;
    __syncthreads();

    // layer 1: M=20, N=128, K=34.  thread: rows r0..r0+4, cols c0,c0+1
    {
        const int r0 = (t >> 6) * 5, c0 = (t & 63) * 2;
        float acc[5][2] = {};
        #pragma unroll 2
        for (int k = 0; k < D_IN; ++k) {
            float2 w = *(const float2*)&w1t[k*E1 + c0];
            #pragma unroll
            for (int i = 0; i < 5; ++i) {
                float xv = xs[(r0+i)*XS + k];
                acc[i][0] += xv * w.x; acc[i][1] += xv * w.y;
            }
        }
        float bb0 = b1[c0], bb1 = b1[c0+1];
        #pragma unroll
        for (int i = 0; i < 5; ++i) {
            float2 h;
            h.x = fmaxf(acc[i][0] + bb0, 0.f);
            h.y = fmaxf(acc[i][1] + bb1, 0.f);
            *(float2*)&h1s[(r0+i)*130 + c0] = h;
        }
    }
    __syncthreads();

    // layer 2: M=20, N=256, K=128.  thread: rows r0..r0+4, cols c0..c0+3
    {
        const int r0 = (t >> 6) * 5, c0 = (t & 63) * 4;
        float acc[5][4] = {};
        const float4* w2t4 = (const float4*)(ws + OFF_W2T);
        #pragma unroll 8
        for (int k = 0; k < E1; ++k) {
            float4 w = w2t4[k*64 + (t & 63)];         // 1 KB/wave, coalesced
            #pragma unroll
            for (int i = 0; i < 5; ++i) {
                float hv = h1s[(r0+i)*130 + k];       // broadcast
                acc[i][0] += hv*w.x; acc[i][1] += hv*w.y;
                acc[i][2] += hv*w.z; acc[i][3] += hv*w.w;
            }
        }
        float4 bb = *(const float4*)&b2[c0];
        float s1[4] = {}, s2[4] = {};
        #pragma unroll
        for (int i = 0; i < 5; ++i) {
            float4 v;
            v.x = fmaxf(acc[i][0] + bb.x, 0.f);
            v.y = fmaxf(acc[i][1] + bb.y, 0.f);
            v.z = fmaxf(acc[i][2] + bb.z, 0.f);
            v.w = fmaxf(acc[i][3] + bb.w, 0.f);
            *(float4*)&ws[OFF_H2 + (size_t)(row0 + r0 + i)*E2 + c0] = v;
            s1[0] += v.x; s1[1] += v.y; s1[2] += v.z; s1[3] += v.w;
            s2[0] += v.x*v.x; s2[1] += v.y*v.y; s2[2] += v.z*v.z; s2[3] += v.w*v.w;
        }
        #pragma unroll
        for (int j = 0; j < 4; ++j) {
            atomicAdd(&ls1[c0+j], s1[j]);
            atomicAdd(&ls2[c0+j], s2[j]);
        }
    }
    __syncthreads();
    atomicAdd(&ws[OFF_ST + (size_t)b*E2 + t], ls1[t]);
    atomicAdd(&ws[OFF_ST + (size_t)BB*E2 + (size_t)b*E2 + t], ls2[t]);
}

// ---- kC: norm + layers 3,4 + contiguous penalty fill + scatter ------------
__global__ __launch_bounds__(256) void kC_out(
    const float* __restrict__ b3, const float* __restrict__ b4,
    const float* __restrict__ gamma, const float* __restrict__ beta,
    const float* __restrict__ ws, float* __restrict__ out)
{
    const int row0 = blockIdx.x * RB;
    const int b = row0 / NN;
    const int t = threadIdx.x;

    __shared__ float Aaf[E2], Baf[E2];
    __shared__ float hn[RB * 260];         // 20.8 KB (16B-aligned rows)
    __shared__ float h3s[RB * 132];        // 10.6 KB
    __shared__ float sds[RB*KK]; __shared__ int sis[RB*KK];
    __shared__ float ov[RB*KK];

    // per-channel affine: hn = v*A + B  (A = gamma/sigma, B = beta - mu*A)
    {
        float s1 = ws[OFF_ST + (size_t)b*E2 + t];
        float s2 = ws[OFF_ST + (size_t)BB*E2 + (size_t)b*E2 + t];
        float mu  = s1 / (float)NN;
        float var = s2 / (float)NN - mu*mu;
        float inv = 1.0f / sqrtf(var + EPSV);
        float A = inv * gamma[t];
        Aaf[t] = A; Baf[t] = beta[t] - mu * A;
    }
    for (int i = t; i < RB*KK; i += 256) {
        int r = i >> 4, oc = i & 15;
        sds[i] = ws[OFF_X + (size_t)(row0 + r)*XS + oc];
        sis[i] = ((const int*)(ws + OFF_SI))[(size_t)(row0 + r)*KK + oc];
    }
    __syncthreads();

    // stage normalized h2
    for (int q = t; q < RB*64; q += 256) {
        int r = q >> 6, c4 = (q & 63) * 4;
        float4 v = *(const float4*)&ws[OFF_H2 + (size_t)(row0 + r)*E2 + c4];
        v.x = v.x*Aaf[c4+0] + Baf[c4+0];
        v.y = v.y*Aaf[c4+1] + Baf[c4+1];
        v.z = v.z*Aaf[c4+2] + Baf[c4+2];
        v.w = v.w*Aaf[c4+3] + Baf[c4+3];
        *(float4*)&hn[r*260 + c4] = v;
    }
    __syncthreads();

    // layer 3: M=20, N=128, K=256.  thread: rows r0..r0+4, cols c0,c0+1
    {
        const int r0 = (t >> 6) * 5, c0 = (t & 63) * 2;
        float acc[5][2] = {};
        const float2* w3t2 = (const float2*)(ws + OFF_W3T);
        #pragma unroll 8
        for (int k = 0; k < E2; ++k) {
            float2 w = w3t2[k*64 + (t & 63)];         // 512B/wave, coalesced
            #pragma unroll
            for (int i = 0; i < 5; ++i) {
                float hv = hn[(r0+i)*260 + k];        // broadcast
                acc[i][0] += hv*w.x; acc[i][1] += hv*w.y;
            }
        }
        float bb0 = b3[c0], bb1 = b3[c0+1];
        #pragma unroll
        for (int i = 0; i < 5; ++i) {
            float2 h;
            h.x = fmaxf(acc[i][0] + bb0, 0.f);
            h.y = fmaxf(acc[i][1] + bb1, 0.f);
            *(float2*)&h3s[(r0+i)*132 + c0] = h;
        }
    }
    __syncthreads();

    // layer 4: 320 outputs (20 rows x 16), K=128
    for (int oidx = t; oidx < RB*KK; oidx += 256) {
        int r = oidx >> 4, oc = oidx & 15;
        float acc = b4[oc];
        const float* w4t = ws + OFF_W4T;
        #pragma unroll 8
        for (int k = 0; k < E1; ++k)
            acc += h3s[r*132 + k] * w4t[k*KK + oc];
        ov[oidx] = acc - sds[oidx];
    }
    __syncthreads();

    // penalty fill: 20 contiguous rows = 160 KB flat
    {
        float4* ob = (float4*)(out + (size_t)row0 * MM);
        const float4 pv = make_float4(PEN, PEN, PEN, PEN);
        for (int j = t; j < RB*MM/4; j += 256) ob[j] = pv;
    }
    __syncthreads();
    for (int i = t; i < RB*KK; i += 256) {
        int r = i >> 4;
        out[(size_t)(row0 + r)*MM + sis[i]] = ov[i];
    }
}

extern "C" void kernel_launch(void* const* d_in, const int* in_sizes, int n_in,
                              void* d_out, int out_size, void* d_ws, size_t ws_size,
                              hipStream_t stream) {
    const float* theta = (const float*)d_in[0];
    const float* dist  = (const float*)d_in[1];
    const float* ins   = (const float*)d_in[2];
    const float* W1 = (const float*)d_in[3];
    const float* b1 = (const float*)d_in[4];
    const float* W2 = (const float*)d_in[5];
    const float* b2 = (const float*)d_in[6];
    const float* W3 = (const float*)d_in[7];
    const float* b3 = (const float*)d_in[8];
    const float* W4 = (const float*)d_in[9];
    const float* b4 = (const float*)d_in[10];
    const float* gamma = (const float*)d_in[11];
    const float* beta  = (const float*)d_in[12];
    float* ws  = (float*)d_ws;
    float* out = (float*)d_out;

    hipMemsetAsync(ws + OFF_ST, 0, (size_t)2*BB*E2*sizeof(float), stream);

    {
        int total = E1*E2 + E2*E1 + E1*KK;
        k_prep<<<(total + 255)/256, 256, 0, stream>>>(W2, W3, W4, ws);
    }
    kA_select<<<ROWS, 256, 0, stream>>>(theta, dist, ins, ws);
    kB_mlp12<<<ROWS/RB, 256, 0, stream>>>(W1, b1, b2, ws);
    kC_out<<<ROWS/RB, 256, 0, stream>>>(b3, b4, gamma, beta, ws, out);
}